// Round 1
// baseline (11654.721 us; speedup 1.0000x reference)
//
#include <hip/hip_runtime.h>
#include <hip/hip_fp16.h>

typedef _Float16 f16;
typedef _Float16 f16x8 __attribute__((ext_vector_type(8)));
typedef float f32x4 __attribute__((ext_vector_type(4)));

#define TT 512

// ws layout (bytes)
#define XH_OFF    0                 // x as f16: 512*64*256*2 = 16777216
#define WP_OFF    16777216          // packed weights f16: 7340032
#define HA_OFF    24117248          // h_a double buffer: 2*65536
#define HB_OFF    24248320          // h_b double buffer: 2*65536
#define BAR_OFF   24379392          // barrier cnt/gen
#define WS_NEED   24379904

#define WP_L1_HOFF 1572864          // half-offset of layer1 slice in wpack
#define SCRW 20                     // padded row stride (f32) of LDS scratch
#define LDS_BYTES 151552            // 131072 weights + 20480 scratch

// ---------------- prep kernels ----------------

__global__ void k_pack_w(const float* __restrict__ W0, const float* __restrict__ U0,
                         const float* __restrict__ W1, const float* __restrict__ U1,
                         f16* __restrict__ wp) {
  int idx = blockIdx.x * 256 + threadIdx.x;
  if (idx >= 458752) return;
  if (idx < 196608) {              // layer0: [w][ct][s=24][lane]
    int w = idx / 6144, r = idx % 6144;
    int ct = r / 1536, r2 = r % 1536;
    int s = r2 / 64, lane = r2 % 64;
    int g = ct * 512 + w * 16 + (lane & 15);
    int kb = s * 32 + (lane >> 4) * 8;
    f16* dst = wp + (size_t)idx * 8;
#pragma unroll
    for (int j = 0; j < 8; ++j) {
      int k = kb + j;
      float v = (k < 256) ? W0[g * 256 + k] : U0[g * 512 + (k - 256)];
      dst[j] = (f16)v;
    }
  } else {                         // layer1: [w][ct][s=32][lane]
    int i2 = idx - 196608;
    int w = i2 / 8192, r = i2 % 8192;
    int ct = r / 2048, r2 = r % 2048;
    int s = r2 / 64, lane = r2 % 64;
    int g = ct * 512 + w * 16 + (lane & 15);
    int kb = s * 32 + (lane >> 4) * 8;
    f16* dst = wp + (size_t)WP_L1_HOFF + (size_t)i2 * 8;
#pragma unroll
    for (int j = 0; j < 8; ++j) {
      int k = kb + j;
      float v = (k < 512) ? W1[g * 512 + k] : U1[g * 512 + (k - 512)];
      dst[j] = (f16)v;
    }
  }
}

__global__ void k_pack_x(const float* __restrict__ x, f16* __restrict__ xh) {
  int t = blockIdx.x * 256 + threadIdx.x;
  if (t >= 1048576) return;
  const float4* s = (const float4*)(x) + (size_t)t * 2;
  float4 a = s[0], b = s[1];
  f16x8 o;
  o[0] = (f16)a.x; o[1] = (f16)a.y; o[2] = (f16)a.z; o[3] = (f16)a.w;
  o[4] = (f16)b.x; o[5] = (f16)b.y; o[6] = (f16)b.z; o[7] = (f16)b.w;
  *(f16x8*)(xh + (size_t)t * 8) = o;
}

__global__ void k_init(const float* __restrict__ h0, f16* __restrict__ ha,
                       f16* __restrict__ hb, unsigned* __restrict__ bar) {
  int i = blockIdx.x * 256 + threadIdx.x;
  if (i < 32768) {
    ha[i] = (f16)h0[i];                    // h_a buf0 <- h0[0]
  } else if (i < 65536) {
    hb[i] = (f16)h0[i];                    // h_b buf1 <- h0[1] (i-32768 into buf1)
  }
  if (i == 0) { bar[0] = 0u; bar[1] = 0u; }
}

// ---------------- math helpers ----------------

__device__ __forceinline__ float sigmoidf_(float x) {
  return 1.0f / (1.0f + __expf(-x));
}
__device__ __forceinline__ float tanhf_(float x) {
  x = fminf(fmaxf(x, -15.0f), 15.0f);
  float e = __expf(-2.0f * x);
  return (1.0f - e) / (1.0f + e);
}

// ---------------- persistent LSTM ----------------

template <int LAYER>
__device__ void lstm_body(const f16* __restrict__ xh, const f16* __restrict__ wp,
                          f16* __restrict__ ha, f16* __restrict__ hb,
                          unsigned* __restrict__ bar, const float* __restrict__ c0,
                          const float* __restrict__ bb, float* __restrict__ dout,
                          f16* lds) {
  constexpr int NK = LAYER ? 32 : 24;       // K-steps (K=32 each)
  const int w = blockIdx.x & 31;
  const int tid = threadIdx.x, lane = tid & 63, wv = tid >> 6;
  const int wm = wv >> 1, wn = wv & 1;

  // copy this WG's weight slice into LDS (once; reused 512 steps)
  {
    const uint4* src = (const uint4*)(wp + (LAYER ? (size_t)WP_L1_HOFF + (size_t)w * 65536
                                                  : (size_t)w * 49152));
    uint4* dst = (uint4*)lds;
    const int n16 = LAYER ? 8192 : 6144;    // halfs/8
    for (int i = tid; i < n16; i += 256) dst[i] = src[i];
  }

  const int j15 = lane & 15;
  const int l4 = lane >> 4;
  const int hidb = w * 16 + j15;
  const float bi = bb[hidb], bf = bb[512 + hidb], bo = bb[1024 + hidb], bc = bb[1536 + hidb];

  float cr[4];
#pragma unroll
  for (int r = 0; r < 4; ++r) {
    int n = 16 * wv + l4 * 4 + r;
    cr[r] = c0[(size_t)LAYER * 32768 + n * 512 + hidb];
  }

  float* scr = (float*)(lds + 65536);       // byte offset 131072
  const int koff = l4 * 8;
  __syncthreads();

  bool broken = false;
  for (int p = 0; p <= TT; ++p) {
    const f16* hard = ha + (p & 1) * 32768;
    const f16* hbrd = hb + (p & 1) * 32768;
    f16* hwr = (LAYER == 0 ? ha : hb) + (((p & 1) ^ 1) * 32768);
    const bool active = (LAYER == 0) ? (p < TT) : (p >= 1);

    if (active) {
      f32x4 acc[2][2];
#pragma unroll
      for (int a = 0; a < 2; ++a)
#pragma unroll
        for (int b2 = 0; b2 < 2; ++b2) acc[a][b2] = (f32x4){0.f, 0.f, 0.f, 0.f};

      auto lda = [&](int s, int mi) -> uint4 {
        const int row = 32 * wm + 16 * mi + j15;
        const f16* p2;
        if (LAYER == 0) {
          if (s < 8) p2 = xh + ((size_t)p * 64 + row) * 256 + s * 32 + koff;
          else       p2 = hard + row * 512 + (s - 8) * 32 + koff;
        } else {
          if (s < 16) p2 = hard + row * 512 + s * 32 + koff;
          else        p2 = hbrd + row * 512 + (s - 16) * 32 + koff;
        }
        return *(const uint4*)p2;
      };

      uint4 ab[8][2];
#pragma unroll
      for (int s = 0; s < 8; ++s) { ab[s][0] = lda(s, 0); ab[s][1] = lda(s, 1); }

#pragma unroll
      for (int s = 0; s < NK; ++s) {
        f16x8 b0 = *(const f16x8*)(lds + ((((2 * wn + 0) * NK + s) * 64 + lane) * 8));
        f16x8 b1 = *(const f16x8*)(lds + ((((2 * wn + 1) * NK + s) * 64 + lane) * 8));
        f16x8 a0 = __builtin_bit_cast(f16x8, ab[s & 7][0]);
        f16x8 a1 = __builtin_bit_cast(f16x8, ab[s & 7][1]);
        acc[0][0] = __builtin_amdgcn_mfma_f32_16x16x32_f16(a0, b0, acc[0][0], 0, 0, 0);
        acc[0][1] = __builtin_amdgcn_mfma_f32_16x16x32_f16(a0, b1, acc[0][1], 0, 0, 0);
        acc[1][0] = __builtin_amdgcn_mfma_f32_16x16x32_f16(a1, b0, acc[1][0], 0, 0, 0);
        acc[1][1] = __builtin_amdgcn_mfma_f32_16x16x32_f16(a1, b1, acc[1][1], 0, 0, 0);
        if (s + 8 < NK) { ab[s & 7][0] = lda(s + 8, 0); ab[s & 7][1] = lda(s + 8, 1); }
      }

      // scatter gate preactivations to LDS scratch: [gate][row 0..63][hid 0..15]
#pragma unroll
      for (int mi = 0; mi < 2; ++mi)
#pragma unroll
        for (int ni = 0; ni < 2; ++ni)
#pragma unroll
          for (int r = 0; r < 4; ++r) {
            int row = 32 * wm + 16 * mi + l4 * 4 + r;
            int ct = 2 * wn + ni;
            scr[(ct * 64 + row) * SCRW + j15] = acc[mi][ni][r];
          }
      __syncthreads();

      const bool last = (p == (LAYER ? TT : TT - 1));
#pragma unroll
      for (int r = 0; r < 4; ++r) {
        int n = 16 * wv + l4 * 4 + r;
        float gi = scr[(0 * 64 + n) * SCRW + j15] + bi;
        float gf = scr[(1 * 64 + n) * SCRW + j15] + bf;
        float go = scr[(2 * 64 + n) * SCRW + j15] + bo;
        float gc = scr[(3 * 64 + n) * SCRW + j15] + bc;
        float ig = sigmoidf_(gi), fg = sigmoidf_(gf), og = sigmoidf_(go);
        float cg = tanhf_(gc);
        float c = fg * cr[r] + ig * cg;
        cr[r] = c;
        float h = og * tanhf_(c);
        hwr[n * 512 + hidb] = (f16)h;
        if (last) {
          dout[8192 + LAYER * 32768 + n * 512 + hidb] = h;
          dout[73728 + LAYER * 32768 + n * 512 + hidb] = c;
        }
      }
    }

    // ---- grid barrier (release stores, arrive, spin, acquire) ----
    __threadfence();
    __syncthreads();
    if (tid == 0 && !broken) {
      unsigned g = __hip_atomic_load(bar + 1, __ATOMIC_RELAXED, __HIP_MEMORY_SCOPE_AGENT);
      unsigned prev = __hip_atomic_fetch_add(bar, 1u, __ATOMIC_ACQ_REL, __HIP_MEMORY_SCOPE_AGENT);
      if (prev == 63u) {
        __hip_atomic_store(bar, 0u, __ATOMIC_RELAXED, __HIP_MEMORY_SCOPE_AGENT);
        __hip_atomic_store(bar + 1, g + 1u, __ATOMIC_RELEASE, __HIP_MEMORY_SCOPE_AGENT);
      } else {
        unsigned spins = 0;
        while (__hip_atomic_load(bar + 1, __ATOMIC_RELAXED, __HIP_MEMORY_SCOPE_AGENT) == g) {
          __builtin_amdgcn_s_sleep(2);
          if (++spins > (1u << 22)) { broken = true; break; }
        }
      }
      __threadfence();   // acquire side: invalidate L1/L2 so fresh h is visible
    }
    __syncthreads();
  }
}

__global__ __launch_bounds__(256, 1) void k_lstm(const f16* __restrict__ xh,
                                                 const f16* __restrict__ wp,
                                                 f16* __restrict__ ha, f16* __restrict__ hb,
                                                 unsigned* __restrict__ bar,
                                                 const float* __restrict__ c0,
                                                 const float* __restrict__ b0,
                                                 const float* __restrict__ b1,
                                                 float* __restrict__ dout) {
  extern __shared__ f16 lds[];
  if (blockIdx.x < 32) lstm_body<0>(xh, wp, ha, hb, bar, c0, b0, dout, lds);
  else                 lstm_body<1>(xh, wp, ha, hb, bar, c0, b1, dout, lds);
}

// ---------------- final FC ----------------

__global__ void k_fc(const float* __restrict__ hn1, const float* __restrict__ fcw,
                     const float* __restrict__ fcb, float* __restrict__ out) {
  int n = blockIdx.x, cc = threadIdx.x;   // 64 x 128
  const float* h = hn1 + n * 512;
  const float* wr = fcw + cc * 512;
  float s = fcb[cc];
#pragma unroll 4
  for (int k = 0; k < 512; k += 4) {
    float4 hv = *(const float4*)(h + k);
    float4 wv = *(const float4*)(wr + k);
    s += hv.x * wv.x + hv.y * wv.y + hv.z * wv.z + hv.w * wv.w;
  }
  out[n * 128 + cc] = s;
}

// ---------------- launch ----------------

extern "C" void kernel_launch(void* const* d_in, const int* in_sizes, int n_in,
                              void* d_out, int out_size, void* d_ws, size_t ws_size,
                              hipStream_t stream) {
  const float* x   = (const float*)d_in[0];
  const float* h0  = (const float*)d_in[1];
  const float* c0  = (const float*)d_in[2];
  const float* W0  = (const float*)d_in[3];
  const float* U0  = (const float*)d_in[4];
  const float* b0  = (const float*)d_in[5];
  const float* W1  = (const float*)d_in[6];
  const float* U1  = (const float*)d_in[7];
  const float* b1  = (const float*)d_in[8];
  const float* fcw = (const float*)d_in[9];
  const float* fcb = (const float*)d_in[10];
  float* out = (float*)d_out;
  char* ws = (char*)d_ws;
  if (ws_size < (size_t)WS_NEED) return;

  f16* xh = (f16*)(ws + XH_OFF);
  f16* wp = (f16*)(ws + WP_OFF);
  f16* ha = (f16*)(ws + HA_OFF);
  f16* hb = (f16*)(ws + HB_OFF);
  unsigned* bar = (unsigned*)(ws + BAR_OFF);

  (void)hipFuncSetAttribute((const void*)k_lstm,
                            hipFuncAttributeMaxDynamicSharedMemorySize, LDS_BYTES);

  k_pack_w<<<(458752 + 255) / 256, 256, 0, stream>>>(W0, U0, W1, U1, wp);
  k_pack_x<<<(1048576 + 255) / 256, 256, 0, stream>>>(x, xh);
  k_init<<<256, 256, 0, stream>>>(h0, ha, hb, bar);
  k_lstm<<<64, 256, LDS_BYTES, stream>>>(xh, wp, ha, hb, bar, c0, b0, b1, out);
  k_fc<<<64, 128, 0, stream>>>(out + 8192 + 32768, fcw, fcb, out);
}

// Round 2
// 9343.052 us; speedup vs baseline: 1.2474x; 1.2474x over previous
//
#include <hip/hip_runtime.h>
#include <hip/hip_fp16.h>

typedef _Float16 f16;
typedef _Float16 f16x8 __attribute__((ext_vector_type(8)));
typedef float f32x4 __attribute__((ext_vector_type(4)));

#define TT 512

// ws layout (bytes)
#define XH_OFF    0                 // x as f16: 512*64*256*2 = 16777216
#define WP_OFF    16777216          // packed weights f16: 7340032
#define HA_OFF    24117248          // h_a double buffer: 2*65536
#define HB_OFF    24248320          // h_b double buffer: 2*65536
#define BAR_OFF   24379392          // barrier cnt/gen (monotone)
#define WS_NEED   24379904

#define WP_L1_HOFF 1572864          // half-offset of layer1 slice in wpack
#define SCRW 20                 // padded row stride (f32) of LDS scratch
#define LDS_BYTES 151552            // 131072 weights + 20480 scratch

// ---------------- prep kernels ----------------

__global__ void k_pack_w(const float* __restrict__ W0, const float* __restrict__ U0,
                         const float* __restrict__ W1, const float* __restrict__ U1,
                         f16* __restrict__ wp) {
  int idx = blockIdx.x * 256 + threadIdx.x;
  if (idx >= 458752) return;
  if (idx < 196608) {              // layer0: [w][ct][s=24][lane]
    int w = idx / 6144, r = idx % 6144;
    int ct = r / 1536, r2 = r % 1536;
    int s = r2 / 64, lane = r2 % 64;
    int g = ct * 512 + w * 16 + (lane & 15);
    int kb = s * 32 + (lane >> 4) * 8;
    f16* dst = wp + (size_t)idx * 8;
#pragma unroll
    for (int j = 0; j < 8; ++j) {
      int k = kb + j;
      float v = (k < 256) ? W0[g * 256 + k] : U0[g * 512 + (k - 256)];
      dst[j] = (f16)v;
    }
  } else {                         // layer1: [w][ct][s=32][lane]
    int i2 = idx - 196608;
    int w = i2 / 8192, r = i2 % 8192;
    int ct = r / 2048, r2 = r % 2048;
    int s = r2 / 64, lane = r2 % 64;
    int g = ct * 512 + w * 16 + (lane & 15);
    int kb = s * 32 + (lane >> 4) * 8;
    f16* dst = wp + (size_t)WP_L1_HOFF + (size_t)i2 * 8;
#pragma unroll
    for (int j = 0; j < 8; ++j) {
      int k = kb + j;
      float v = (k < 512) ? W1[g * 512 + k] : U1[g * 512 + (k - 512)];
      dst[j] = (f16)v;
    }
  }
}

__global__ void k_pack_x(const float* __restrict__ x, f16* __restrict__ xh) {
  int t = blockIdx.x * 256 + threadIdx.x;
  if (t >= 1048576) return;
  const float4* s = (const float4*)(x) + (size_t)t * 2;
  float4 a = s[0], b = s[1];
  f16x8 o;
  o[0] = (f16)a.x; o[1] = (f16)a.y; o[2] = (f16)a.z; o[3] = (f16)a.w;
  o[4] = (f16)b.x; o[5] = (f16)b.y; o[6] = (f16)b.z; o[7] = (f16)b.w;
  *(f16x8*)(xh + (size_t)t * 8) = o;
}

__global__ void k_init(const float* __restrict__ h0, f16* __restrict__ ha,
                       f16* __restrict__ hb, unsigned* __restrict__ bar) {
  int i = blockIdx.x * 256 + threadIdx.x;
  if (i < 32768) {
    ha[i] = (f16)h0[i];                    // h_a buf0 <- h0[0]
  } else if (i < 65536) {
    hb[i] = (f16)h0[i];                    // h_b buf1 <- h0[1] (i-32768 into buf1)
  }
  if (i == 0) { bar[0] = 0u; bar[1] = 0u; }
}

// ---------------- math helpers ----------------

__device__ __forceinline__ float sigmoidf_(float x) {
  return 1.0f / (1.0f + __expf(-x));
}
__device__ __forceinline__ float tanhf_(float x) {
  x = fminf(fmaxf(x, -15.0f), 15.0f);
  float e = __expf(-2.0f * x);
  return (1.0f - e) / (1.0f + e);
}

__device__ __forceinline__ unsigned long long ld_coh64(const void* p) {
  return __hip_atomic_load((const unsigned long long*)p, __ATOMIC_RELAXED,
                           __HIP_MEMORY_SCOPE_AGENT);
}

// ---------------- persistent LSTM ----------------

template <int LAYER>
__device__ void lstm_body(const f16* __restrict__ xh, const f16* __restrict__ wp,
                          f16* __restrict__ ha, f16* __restrict__ hb,
                          unsigned* __restrict__ bar, const float* __restrict__ c0,
                          const float* __restrict__ bb, float* __restrict__ dout,
                          f16* lds) {
  constexpr int NK = LAYER ? 32 : 24;       // K-steps (K=32 each)
  const int w = blockIdx.x & 31;
  const int tid = threadIdx.x, lane = tid & 63, wv = tid >> 6;
  const int wm = wv >> 1, wn = wv & 1;

  // copy this WG's weight slice into LDS (once; reused 512 steps)
  {
    const uint4* src = (const uint4*)(wp + (LAYER ? (size_t)WP_L1_HOFF + (size_t)w * 65536
                                                  : (size_t)w * 49152));
    uint4* dst = (uint4*)lds;
    const int n16 = LAYER ? 8192 : 6144;    // halfs/8
    for (int i = tid; i < n16; i += 256) dst[i] = src[i];
  }

  const int j15 = lane & 15;
  const int l4 = lane >> 4;
  const int hidb = w * 16 + j15;
  const float bi = bb[hidb], bf = bb[512 + hidb], bo = bb[1024 + hidb], bc = bb[1536 + hidb];

  float cr[4];
#pragma unroll
  for (int r = 0; r < 4; ++r) {
    int n = 16 * wv + l4 * 4 + r;
    cr[r] = c0[(size_t)LAYER * 32768 + n * 512 + hidb];
  }

  float* scr = (float*)(lds + 65536);       // byte offset 131072
  const int koff = l4 * 8;
  __syncthreads();

  bool broken = false;
  for (int p = 0; p <= TT; ++p) {
    const f16* hard = ha + (p & 1) * 32768;
    const f16* hbrd = hb + (p & 1) * 32768;
    f16* hwr = (LAYER == 0 ? ha : hb) + (((p & 1) ^ 1) * 32768);
    const bool active = (LAYER == 0) ? (p < TT) : (p >= 1);

    if (active) {
      f32x4 acc[2][2];
#pragma unroll
      for (int a = 0; a < 2; ++a)
#pragma unroll
        for (int b2 = 0; b2 < 2; ++b2) acc[a][b2] = (f32x4){0.f, 0.f, 0.f, 0.f};

      // coherent (agent-scope, L1/L2-bypassing) 16B read of h as 2x b64
      auto ldh = [&](const f16* p2) -> uint4 {
        unsigned long long lo = ld_coh64(p2);
        unsigned long long hi = ld_coh64(p2 + 4);
        uint4 r;
        r.x = (unsigned)lo; r.y = (unsigned)(lo >> 32);
        r.z = (unsigned)hi; r.w = (unsigned)(hi >> 32);
        return r;
      };
      auto lda = [&](int s, int mi) -> uint4 {
        const int row = 32 * wm + 16 * mi + j15;
        if (LAYER == 0) {
          if (s < 8) return *(const uint4*)(xh + ((size_t)p * 64 + row) * 256 + s * 32 + koff);
          return ldh(hard + row * 512 + (s - 8) * 32 + koff);
        } else {
          if (s < 16) return ldh(hard + row * 512 + s * 32 + koff);
          return ldh(hbrd + row * 512 + (s - 16) * 32 + koff);
        }
      };

      uint4 ab[8][2];
#pragma unroll
      for (int s = 0; s < 8; ++s) { ab[s][0] = lda(s, 0); ab[s][1] = lda(s, 1); }

#pragma unroll
      for (int s = 0; s < NK; ++s) {
        f16x8 b0 = *(const f16x8*)(lds + ((((2 * wn + 0) * NK + s) * 64 + lane) * 8));
        f16x8 b1 = *(const f16x8*)(lds + ((((2 * wn + 1) * NK + s) * 64 + lane) * 8));
        f16x8 a0 = __builtin_bit_cast(f16x8, ab[s & 7][0]);
        f16x8 a1 = __builtin_bit_cast(f16x8, ab[s & 7][1]);
        acc[0][0] = __builtin_amdgcn_mfma_f32_16x16x32_f16(a0, b0, acc[0][0], 0, 0, 0);
        acc[0][1] = __builtin_amdgcn_mfma_f32_16x16x32_f16(a0, b1, acc[0][1], 0, 0, 0);
        acc[1][0] = __builtin_amdgcn_mfma_f32_16x16x32_f16(a1, b0, acc[1][0], 0, 0, 0);
        acc[1][1] = __builtin_amdgcn_mfma_f32_16x16x32_f16(a1, b1, acc[1][1], 0, 0, 0);
        if (s + 8 < NK) { ab[s & 7][0] = lda(s + 8, 0); ab[s & 7][1] = lda(s + 8, 1); }
      }

      // scatter gate preactivations to LDS scratch: [gate][row 0..63][hid 0..15]
#pragma unroll
      for (int mi = 0; mi < 2; ++mi)
#pragma unroll
        for (int ni = 0; ni < 2; ++ni)
#pragma unroll
          for (int r = 0; r < 4; ++r) {
            int row = 32 * wm + 16 * mi + l4 * 4 + r;
            int ct = 2 * wn + ni;
            scr[(ct * 64 + row) * SCRW + j15] = acc[mi][ni][r];
          }
      __syncthreads();

      const bool last = (p == (LAYER ? TT : TT - 1));
#pragma unroll
      for (int r = 0; r < 4; ++r) {
        int n = 16 * wv + l4 * 4 + r;
        float gi = scr[(0 * 64 + n) * SCRW + j15] + bi;
        float gf = scr[(1 * 64 + n) * SCRW + j15] + bf;
        float go = scr[(2 * 64 + n) * SCRW + j15] + bo;
        float gc = scr[(3 * 64 + n) * SCRW + j15] + bc;
        float ig = sigmoidf_(gi), fg = sigmoidf_(gf), og = sigmoidf_(go);
        float cg = tanhf_(gc);
        float c = fg * cr[r] + ig * cg;
        cr[r] = c;
        float h = og * tanhf_(c);
        // pack (even,odd) hid pair across lane pair; write-through coherent store
        unsigned short us = __builtin_bit_cast(unsigned short, (f16)h);
        unsigned other = __shfl_xor((unsigned)us, 1, 64);
        if (!(lane & 1)) {
          unsigned pack = (unsigned)us | (other << 16);
          __hip_atomic_store((unsigned*)(hwr + n * 512 + hidb), pack,
                             __ATOMIC_RELAXED, __HIP_MEMORY_SCOPE_AGENT);
        }
        if (last) {
          dout[8192 + LAYER * 32768 + n * 512 + hidb] = h;
          dout[73728 + LAYER * 32768 + n * 512 + hidb] = c;
        }
      }
    }

    // ---- grid barrier: no cache maintenance, monotone count + generation ----
    asm volatile("s_waitcnt vmcnt(0)" ::: "memory");  // h write-through stores done
    __syncthreads();
    if (tid == 0 && !broken) {
      unsigned prev = __hip_atomic_fetch_add(bar, 1u, __ATOMIC_RELAXED,
                                             __HIP_MEMORY_SCOPE_AGENT);
      if (prev == (unsigned)(64 * p + 63)) {
        __hip_atomic_store(bar + 1, (unsigned)(p + 1), __ATOMIC_RELAXED,
                           __HIP_MEMORY_SCOPE_AGENT);
      } else {
        unsigned spins = 0;
        while (__hip_atomic_load(bar + 1, __ATOMIC_RELAXED,
                                 __HIP_MEMORY_SCOPE_AGENT) < (unsigned)(p + 1)) {
          __builtin_amdgcn_s_sleep(1);
          if (++spins > (1u << 24)) { broken = true; break; }
        }
      }
    }
    __syncthreads();
  }
}

__global__ __launch_bounds__(256, 1) void k_lstm(const f16* __restrict__ xh,
                                                 const f16* __restrict__ wp,
                                                 f16* __restrict__ ha, f16* __restrict__ hb,
                                                 unsigned* __restrict__ bar,
                                                 const float* __restrict__ c0,
                                                 const float* __restrict__ b0,
                                                 const float* __restrict__ b1,
                                                 float* __restrict__ dout) {
  extern __shared__ f16 lds[];
  if (blockIdx.x < 32) lstm_body<0>(xh, wp, ha, hb, bar, c0, b0, dout, lds);
  else                 lstm_body<1>(xh, wp, ha, hb, bar, c0, b1, dout, lds);
}

// ---------------- final FC ----------------

__global__ void k_fc(const float* __restrict__ hn1, const float* __restrict__ fcw,
                     const float* __restrict__ fcb, float* __restrict__ out) {
  int n = blockIdx.x, cc = threadIdx.x;   // 64 x 128
  const float* h = hn1 + n * 512;
  const float* wr = fcw + cc * 512;
  float s = fcb[cc];
#pragma unroll 4
  for (int k = 0; k < 512; k += 4) {
    float4 hv = *(const float4*)(h + k);
    float4 wv = *(const float4*)(wr + k);
    s += hv.x * wv.x + hv.y * wv.y + hv.z * wv.z + hv.w * wv.w;
  }
  out[n * 128 + cc] = s;
}

// ---------------- launch ----------------

extern "C" void kernel_launch(void* const* d_in, const int* in_sizes, int n_in,
                              void* d_out, int out_size, void* d_ws, size_t ws_size,
                              hipStream_t stream) {
  const float* x   = (const float*)d_in[0];
  const float* h0  = (const float*)d_in[1];
  const float* c0  = (const float*)d_in[2];
  const float* W0  = (const float*)d_in[3];
  const float* U0  = (const float*)d_in[4];
  const float* b0  = (const float*)d_in[5];
  const float* W1  = (const float*)d_in[6];
  const float* U1  = (const float*)d_in[7];
  const float* b1  = (const float*)d_in[8];
  const float* fcw = (const float*)d_in[9];
  const float* fcb = (const float*)d_in[10];
  float* out = (float*)d_out;
  char* ws = (char*)d_ws;
  if (ws_size < (size_t)WS_NEED) return;

  f16* xh = (f16*)(ws + XH_OFF);
  f16* wp = (f16*)(ws + WP_OFF);
  f16* ha = (f16*)(ws + HA_OFF);
  f16* hb = (f16*)(ws + HB_OFF);
  unsigned* bar = (unsigned*)(ws + BAR_OFF);

  (void)hipFuncSetAttribute((const void*)k_lstm,
                            hipFuncAttributeMaxDynamicSharedMemorySize, LDS_BYTES);

  k_pack_w<<<(458752 + 255) / 256, 256, 0, stream>>>(W0, U0, W1, U1, wp);
  k_pack_x<<<(1048576 + 255) / 256, 256, 0, stream>>>(x, xh);
  k_init<<<256, 256, 0, stream>>>(h0, ha, hb, bar);
  k_lstm<<<64, 256, LDS_BYTES, stream>>>(xh, wp, ha, hb, bar, c0, b0, b1, out);
  k_fc<<<64, 128, 0, stream>>>(out + 8192 + 32768, fcw, fcb, out);
}